// Round 2
// baseline (207.649 us; speedup 1.0000x reference)
//
#include <hip/hip_runtime.h>

// YOLO v1 loss, fused single-pass reduction.
// input_: [B, 30, 7, 7] fp32   (channel-major per image)
// target: [B, 7, 7, 30] fp32   (cell-major, 30 contiguous per cell)
// out   : [1] fp32 scalar loss
//
// One thread per grid cell (N = B*49). Target rows staged through LDS with
// coalesced float4 loads; input read directly (contiguous along cell dim for
// each fixed channel -> <=3 segments per wave-load). Block partial summed via
// wave shuffle + LDS, one float atomicAdd per block.

#define CELLF   64.0f
#define IMGF    448.0f
#define EPSF    1e-6f
#define LAMBDA_COORD 5.0f
#define LAMBDA_NOOBJ 0.5f

__global__ __launch_bounds__(256) void yolo_loss_kernel(
    const float* __restrict__ input,
    const float* __restrict__ target,
    float* __restrict__ out,
    int ncells, float inv_b)
{
    __shared__ float s_t[256 * 30];     // 30720 B
    __shared__ float s_part[4];

    const int tid  = threadIdx.x;
    const int base = blockIdx.x * 256;          // first cell of this block
    const int cells_here = min(256, ncells - base);

    // ---- stage target rows for this block's cells into LDS (coalesced) ----
    if (cells_here == 256) {
        // 256*30 = 7680 floats = 1920 float4 (base*30*4B is 16B-aligned when
        // base is a multiple of 4, which it is: base = blockIdx*256)
        const float4* tg4 = reinterpret_cast<const float4*>(target + (size_t)base * 30);
        float4* s4 = reinterpret_cast<float4*>(s_t);
        #pragma unroll
        for (int i = 0; i < 8; ++i) {
            int idx = tid + i * 256;
            if (idx < 1920) s4[idx] = tg4[idx];
        }
    } else {
        // generic tail (not hit for B=16384, kept for safety)
        int nflt = cells_here * 30;
        for (int i = tid; i < nflt; i += 256)
            s_t[i] = target[(size_t)base * 30 + i];
    }
    __syncthreads();

    float lv = 0.0f;
    const int n = base + tid;
    if (tid < cells_here) {
        const int b    = n / 49;
        const int cell = n - b * 49;
        const int row  = cell / 7;
        const int col  = cell - row * 7;

        // input channel c for this cell lives at input[b*1470 + c*49 + cell]
        const float* xin = input + (size_t)b * 1470 + cell;
        float x[30];
        #pragma unroll
        for (int c = 0; c < 30; ++c) x[c] = xin[c * 49];

        const float* t = s_t + tid * 30;

        const float colf = (float)col * CELLF;
        const float rowf = (float)row * CELLF;

        float iou[2];
        #pragma unroll
        for (int k = 0; k < 2; ++k) {
            const int o = 5 * k;
            float pcx = x[o + 0] * CELLF + colf;
            float pcy = x[o + 1] * CELLF + rowf;
            float pw  = x[o + 2] * IMGF;
            float ph  = x[o + 3] * IMGF;
            float px1 = fminf(fmaxf(pcx - 0.5f * pw, 0.0f), IMGF);
            float py1 = fminf(fmaxf(pcy - 0.5f * ph, 0.0f), IMGF);
            float px2 = fminf(fmaxf(pcx + 0.5f * pw, 0.0f), IMGF);
            float py2 = fminf(fmaxf(pcy + 0.5f * ph, 0.0f), IMGF);

            float tcx = t[o + 0] * CELLF + colf;
            float tcy = t[o + 1] * CELLF + rowf;
            float tw  = t[o + 2] * IMGF;
            float th  = t[o + 3] * IMGF;
            float tx1 = fminf(fmaxf(tcx - 0.5f * tw, 0.0f), IMGF);
            float ty1 = fminf(fmaxf(tcy - 0.5f * th, 0.0f), IMGF);
            float tx2 = fminf(fmaxf(tcx + 0.5f * tw, 0.0f), IMGF);
            float ty2 = fminf(fmaxf(tcy + 0.5f * th, 0.0f), IMGF);

            float iw = fmaxf(fminf(px2, tx2) - fmaxf(px1, tx1), EPSF);
            float ih = fmaxf(fminf(py2, ty2) - fmaxf(py1, ty1), EPSF);
            float inter = iw * ih;
            float area  = (px2 - px1) * (py2 - py1) + (tx2 - tx1) * (ty2 - ty1);
            iou[k] = inter / (area - inter);
        }

        const bool  m      = iou[0] < iou[1];
        const float iouSel = m ? iou[1] : iou[0];
        const float has_obj = (t[4] == 1.0f) ? 1.0f : 0.0f;
        const float no_obj  = 1.0f - has_obj;

        const float s0 = m ? x[5] : x[0];
        const float s1 = m ? x[6] : x[1];
        const float s2 = m ? x[7] : x[2];
        const float s3 = m ? x[8] : x[3];
        const float s4 = m ? x[9] : x[4];

        float d0 = s0 - t[0], d1 = s1 - t[1];
        float coord_e = d0 * d0 + d1 * d1;

        float e2 = sqrtf(s2) - sqrtf(t[2]);
        float e3 = sqrtf(s3) - sqrtf(t[3]);
        float size_e = e2 * e2 + e3 * e3;

        float dc = s4 - iouSel;
        float conf_e = dc * dc;

        float cls_e = 0.0f;
        #pragma unroll
        for (int c = 10; c < 30; ++c) {
            float d = x[c] - t[c];
            cls_e += d * d;
        }

        float noobj_e = x[4] * x[4] + x[9] * x[9];

        lv = has_obj * (LAMBDA_COORD * coord_e + LAMBDA_COORD * size_e + conf_e + cls_e)
           + LAMBDA_NOOBJ * no_obj * noobj_e;
    }

    // ---- reduce: wave shuffle, then cross-wave via LDS ----
    float v = lv;
    #pragma unroll
    for (int off = 32; off > 0; off >>= 1)
        v += __shfl_down(v, off, 64);

    if ((tid & 63) == 0) s_part[tid >> 6] = v;
    __syncthreads();

    if (tid == 0) {
        float tot = s_part[0] + s_part[1] + s_part[2] + s_part[3];
        atomicAdd(out, tot * inv_b);
    }
}

extern "C" void kernel_launch(void* const* d_in, const int* in_sizes, int n_in,
                              void* d_out, int out_size, void* d_ws, size_t ws_size,
                              hipStream_t stream) {
    const float* input  = (const float*)d_in[0];
    const float* target = (const float*)d_in[1];
    float* out = (float*)d_out;

    const int B = in_sizes[0] / (30 * 49);      // 16384
    const int ncells = B * 49;                  // 802816
    const int nblocks = (ncells + 255) / 256;   // 3136

    hipMemsetAsync(out, 0, sizeof(float) * out_size, stream);
    yolo_loss_kernel<<<nblocks, 256, 0, stream>>>(input, target, out, ncells,
                                                  1.0f / (float)B);
}